// Round 1
// baseline (723.962 us; speedup 1.0000x reference)
//
#include <hip/hip_runtime.h>

// SynthesisBlock: style-modulated 3x3 conv, bf16 implicit-GEMM MFMA.
// d_ws layout: [0,16KB) style fp32[16][256]; [16KB,32KB) demod fp32[16][256];
// [32KB, 32KB+1.125MB) repacked bf16 weights Wp[kh][cc][m 256][kw 3][ci 32].
// Requires ws_size >= ~1.2 MiB.

typedef __bf16 bf16;
typedef bf16 bf16x8 __attribute__((ext_vector_type(8)));
typedef bf16 bf16x4 __attribute__((ext_vector_type(4)));
typedef float f32x4 __attribute__((ext_vector_type(4)));

#define GLOBAL_AS __attribute__((address_space(1)))
#define LDS_AS __attribute__((address_space(3)))

// ---------------- prep: style[b][i] = latent[b]·aff_w[i]*sqrt(1/512) + aff_b[i]
__global__ __launch_bounds__(256) void style_k(const float* __restrict__ latent,
                                               const float* __restrict__ aff_w,
                                               const float* __restrict__ aff_b,
                                               float* __restrict__ style) {
  const int wid = blockIdx.x * 4 + (threadIdx.x >> 6);  // 0..4095
  const int lane = threadIdx.x & 63;
  const int b = wid >> 8, i = wid & 255;
  float acc = 0.f;
#pragma unroll
  for (int k = 0; k < 8; ++k) {
    const int l = lane + 64 * k;
    acc += latent[b * 512 + l] * aff_w[i * 512 + l];
  }
#pragma unroll
  for (int off = 32; off > 0; off >>= 1) acc += __shfl_xor(acc, off, 64);
  if (lane == 0) style[b * 256 + i] = acc * 0.04419417382415922f + aff_b[i];
}

// ---------------- prep: demod[b][o] = rsqrt(sum_i wsq[o][i]*style[b][i]^2 + 1e-8)
__global__ __launch_bounds__(256) void demod_k(const float* __restrict__ conv_w,
                                               const float* __restrict__ style,
                                               float* __restrict__ demod) {
  __shared__ float s_wsq[256];
  const int o = blockIdx.x, i = threadIdx.x;
  float wsq = 0.f;
#pragma unroll
  for (int t = 0; t < 9; ++t) {
    const float w = conv_w[(o * 256 + i) * 9 + t];
    wsq += w * w;
  }
  s_wsq[i] = wsq;
  __syncthreads();
  const int wv = threadIdx.x >> 6, lane = threadIdx.x & 63;
  for (int b = wv; b < 16; b += 4) {
    float p = 0.f;
#pragma unroll
    for (int k = 0; k < 4; ++k) {
      const int ii = lane + 64 * k;
      const float s = style[b * 256 + ii];
      p += s_wsq[ii] * s * s;
    }
#pragma unroll
    for (int off = 32; off > 0; off >>= 1) p += __shfl_xor(p, off, 64);
    if (lane == 0) demod[b * 256 + o] = rsqrtf(p + 1e-8f);
  }
}

// ---------------- prep: repack conv_w fp32[o][c][kh][kw] -> bf16 Wp[kh][cc][m][kw][ci]
__global__ __launch_bounds__(256) void wprep_k(const float* __restrict__ conv_w,
                                               bf16* __restrict__ wp) {
  const int idx = blockIdx.x * 256 + threadIdx.x;  // < 589824
  const int ci = idx & 31;
  const int t3 = idx >> 5;
  const int kw = t3 % 3;
  const int t4 = t3 / 3;
  const int m = t4 & 255;
  const int t5 = t4 >> 8;
  const int cc = t5 & 7, kh = t5 >> 3;
  const float v = conv_w[((m * 256 + cc * 32 + ci) * 3 + kh) * 3 + kw];
  wp[idx] = (bf16)v;
}

// ---------------- main conv: block tile M=128 (out ch) x N=128 (one row), 4 waves
__global__ __launch_bounds__(256) void conv_k(const float* __restrict__ content,
                                              const float* __restrict__ noise,
                                              const float* __restrict__ bias,
                                              const float* __restrict__ nwp,
                                              const float* __restrict__ style,
                                              const float* __restrict__ demod,
                                              const bf16* __restrict__ wp,
                                              float* __restrict__ out) {
  // ldsA: [128 m][96 = kw*32+ci] bf16 (24576 B). ldsX: [130 x][40 (32 ci + pad)] bf16 (10400 B).
  __shared__ __align__(16) char smem[24576 + 10400];
  bf16* ldsA = (bf16*)smem;
  bf16* ldsX = (bf16*)(smem + 24576);

  const int tid = threadIdx.x;
  const int lane = tid & 63, wv = tid >> 6;
  const int bid = blockIdx.x;
  const int mt = bid & 1;        // which 128 of 256 out channels
  const int sp = bid >> 1;       // 0..2047
  const int h = sp & 127, b = sp >> 7;
  const int g = lane >> 4, nl = lane & 15;
  const int m0 = (wv & 1) * 64, n0 = (wv >> 1) * 64;
  const int wS = tid & 127, qi = tid >> 7;  // staging: w column, quad parity

  f32x4 acc[4][4];
  const f32x4 zero4 = {0.f, 0.f, 0.f, 0.f};
#pragma unroll
  for (int mb = 0; mb < 4; ++mb)
#pragma unroll
    for (int nb = 0; nb < 4; ++nb) acc[mb][nb] = zero4;

  const float* srcb = content + ((size_t)b * 256) * 16384;

  for (int cc = 0; cc < 8; ++cc) {
    const float* stl = style + b * 256 + cc * 32;
    for (int kh = 0; kh < 3; ++kh) {
      const int gh = h + kh - 1;
      if (gh < 0 || gh >= 128) continue;  // block-uniform: zero-pad rows contribute nothing
      // ---- stage A (weights) via async global->LDS, 24 KiB contiguous
      {
        const bf16* seg = wp + ((size_t)((kh * 8 + cc) * 256 + mt * 128)) * 96;
#pragma unroll
        for (int i = 0; i < 6; ++i) {
          const int u = wv * 384 + i * 64 + lane;  // 16B units
          __builtin_amdgcn_global_load_lds((const GLOBAL_AS void*)(seg + u * 8),
                                           (LDS_AS void*)(ldsA + u * 8), 16, 0, 0);
        }
      }
      // ---- stage X: one input row, 32 channels, modulated + bf16, transposed [x][ci]
      {
        const float* src = srcb + (size_t)(cc * 32) * 16384 + gh * 128 + wS;
#pragma unroll
        for (int jj = 0; jj < 4; ++jj) {
          const int q = qi + jj * 2;  // quad 0..7 = ci 4q..4q+3
          const float v0 = src[(q * 4 + 0) * 16384] * stl[q * 4 + 0];
          const float v1 = src[(q * 4 + 1) * 16384] * stl[q * 4 + 1];
          const float v2 = src[(q * 4 + 2) * 16384] * stl[q * 4 + 2];
          const float v3 = src[(q * 4 + 3) * 16384] * stl[q * 4 + 3];
          bf16x4 pk = {(bf16)v0, (bf16)v1, (bf16)v2, (bf16)v3};
          *(bf16x4*)(ldsX + (wS + 1) * 40 + q * 4) = pk;
        }
        if (tid < 16) {  // halo columns x=0 (w=-1) and x=129 (w=128) are image pad -> 0
          const int xh = (tid >> 3) ? 129 : 0;
          const int q = tid & 7;
          bf16x4 z = {(bf16)0.f, (bf16)0.f, (bf16)0.f, (bf16)0.f};
          *(bf16x4*)(ldsX + xh * 40 + q * 4) = z;
        }
      }
      __syncthreads();
      // ---- compute: 3 kw steps, each one K=32 MFMA step over the 32-channel chunk
#pragma unroll
      for (int kw = 0; kw < 3; ++kw) {
        bf16x8 af[4], xf[4];
#pragma unroll
        for (int mb = 0; mb < 4; ++mb)
          af[mb] = *(const bf16x8*)(ldsA + (m0 + mb * 16 + nl) * 96 + kw * 32 + g * 8);
#pragma unroll
        for (int nb = 0; nb < 4; ++nb)
          xf[nb] = *(const bf16x8*)(ldsX + (n0 + nb * 16 + nl + kw) * 40 + g * 8);
#pragma unroll
        for (int mb = 0; mb < 4; ++mb)
#pragma unroll
          for (int nb = 0; nb < 4; ++nb)
            acc[mb][nb] =
                __builtin_amdgcn_mfma_f32_16x16x32_bf16(af[mb], xf[nb], acc[mb][nb], 0, 0, 0);
      }
      __syncthreads();
    }
  }

  // ---- epilogue: demod, noise, bias, leaky_relu(0.2) * sqrt(2)
  const float nw = nwp[0];
#pragma unroll
  for (int mb = 0; mb < 4; ++mb) {
    const int o = mt * 128 + m0 + mb * 16 + g * 4;  // D row = 4*(lane>>4)+reg
    const f32x4 dm = *(const f32x4*)(demod + b * 256 + o);
    const f32x4 bs = *(const f32x4*)(bias + o);
#pragma unroll
    for (int nb = 0; nb < 4; ++nb) {
      const int wo = n0 + nb * 16 + nl;  // D col = lane&15
      const float nz = nw * noise[b * 16384 + h * 128 + wo];
      float* op = out + ((size_t)(b * 256 + o)) * 16384 + h * 128 + wo;
#pragma unroll
      for (int r = 0; r < 4; ++r) {
        float y = acc[mb][nb][r] * dm[r] + nz + bs[r];
        y = (y > 0.f ? y : 0.2f * y) * 1.41421356237f;
        op[(size_t)r * 16384] = y;
      }
    }
  }
}

extern "C" void kernel_launch(void* const* d_in, const int* in_sizes, int n_in,
                              void* d_out, int out_size, void* d_ws, size_t ws_size,
                              hipStream_t stream) {
  const float* content = (const float*)d_in[0];
  const float* latent = (const float*)d_in[1];
  const float* noise = (const float*)d_in[2];
  const float* aff_w = (const float*)d_in[3];
  const float* aff_b = (const float*)d_in[4];
  const float* conv_w = (const float*)d_in[5];
  const float* bias = (const float*)d_in[6];
  const float* nw = (const float*)d_in[7];
  float* out = (float*)d_out;

  float* style = (float*)d_ws;                       // 16*256 fp32
  float* demod = style + 4096;                       // 16*256 fp32
  bf16* wp = (bf16*)((char*)d_ws + 32768);           // 589824 bf16

  style_k<<<1024, 256, 0, stream>>>(latent, aff_w, aff_b, style);
  demod_k<<<256, 256, 0, stream>>>(conv_w, style, demod);
  wprep_k<<<2304, 256, 0, stream>>>(conv_w, wp);
  conv_k<<<4096, 256, 0, stream>>>(content, noise, bias, nw, style, demod, wp, out);
}